// Round 5
// baseline (17479.443 us; speedup 1.0000x reference)
//
#include <hip/hip_runtime.h>

typedef unsigned short u16;
typedef unsigned long long u64;
typedef short bf16x8 __attribute__((ext_vector_type(8)));
typedef float f32x4 __attribute__((ext_vector_type(4)));
typedef bf16x8 bf16x8_a __attribute__((may_alias));
typedef float f4 __attribute__((ext_vector_type(4)));
typedef f4 f4a __attribute__((may_alias));
typedef u64 u64_a __attribute__((may_alias));

#define MFMA16(a, b, c) __builtin_amdgcn_mfma_f32_16x16x32_bf16((a), (b), (c), 0, 0, 0)

#define AGLD(p) __hip_atomic_load((p), __ATOMIC_RELAXED, __HIP_MEMORY_SCOPE_AGENT)
#define AGST(p, v) __hip_atomic_store((p), (v), __ATOMIC_RELAXED, __HIP_MEMORY_SCOPE_AGENT)

// ---------- helpers ----------
__device__ __forceinline__ u16 f2bf_rne(float x) {
  unsigned u = __float_as_uint(x);
  u += 0x7FFFu + ((u >> 16) & 1u);
  return (u16)(u >> 16);
}
__device__ __forceinline__ short bfr(float x) {  // round-half-up (hot path)
  return (short)((__float_as_uint(x) + 0x8000u) >> 16);
}
__device__ __forceinline__ float bf2f(u16 h) {
  return __uint_as_float(((unsigned)h) << 16);
}
__device__ __forceinline__ float sigmoid_(float x) { return 1.0f / (1.0f + __expf(-x)); }
__device__ __forceinline__ float tanh_(float x) {
  x = fminf(8.0f, fmaxf(-8.0f, x));
  float e = __expf(2.0f * x);
  return (e - 1.0f) / (e + 1.0f);
}
__device__ __forceinline__ bf16x8 ldb8(const u16* p) { return *(const bf16x8_a*)p; }
__device__ __forceinline__ bf16x8 cvt8(const float* p) {
  f4 lo = *(const f4a*)p;
  f4 hi = *(const f4a*)(p + 4);
  bf16x8 v;
  v[0] = bfr(lo[0]); v[1] = bfr(lo[1]); v[2] = bfr(lo[2]); v[3] = bfr(lo[3]);
  v[4] = bfr(hi[0]); v[5] = bfr(hi[1]); v[6] = bfr(hi[2]); v[7] = bfr(hi[3]);
  return v;
}
union U16B {
  u64 q[2];
  u16 h[8];
  bf16x8 v;
};
__device__ __forceinline__ bf16x8 mk8(u64 lo, u64 hi) {
  U16B u;
  u.q[0] = lo;
  u.q[1] = hi;
  return u.v;
}
// chunked-h A-fragment: h[chunk][row] u64; k = 32*ks + quad*8 + j -> chunks 8ks+2q, +1
__device__ __forceinline__ bf16x8 ld_chunk(const u64* hb, int ks, int quad, int row) {
  const int c0 = ks * 512 + (quad << 7) + row;
  return mk8(((const u64_a*)hb)[c0], ((const u64_a*)hb)[c0 + 64]);
}

// ---------- transpose + f32->bf16: out[c][k] = in[k][c] ----------
__global__ __launch_bounds__(256) void transpose_cvt(const float* __restrict__ in,
                                                     u16* __restrict__ out, int R, int C) {
  __shared__ float tile[32][33];
  const int tx = threadIdx.x & 31, ty = threadIdx.x >> 5;
  const int c0 = blockIdx.x * 32, r0 = blockIdx.y * 32;
#pragma unroll
  for (int i = 0; i < 32; i += 8)
    tile[ty + i][tx] = in[(size_t)(r0 + ty + i) * C + (c0 + tx)];
  __syncthreads();
#pragma unroll
  for (int i = 0; i < 32; i += 8)
    out[(size_t)(c0 + ty + i) * R + (r0 + tx)] = f2bf_rne(tile[tx][ty + i]);
}

// ==================== persistent cooperative RNN kernel ====================
// 256 WGs x 256 thr. WG owns h-cols hc0=wg*4..+3 (= chunk wg), all 4 gates.
// h chunked: u64 h[256][64]. Publish = write-through (sc1) 512B + vmcnt drain
// + flag. Readers: per-step fence(acquire, agent) [buffer_inv] then NORMAL
// cached loads -> h shared through the XCD's L2 instead of 256x L3 pulls.
__global__ __launch_bounds__(256, 1) void rnn_persist(
    const float* __restrict__ emb, const int* __restrict__ src, const int* __restrict__ trg,
    const u16* __restrict__ WtE, const u16* __restrict__ WtD,
    const float* __restrict__ encB, const float* __restrict__ decB,
    u64* __restrict__ hA, u64* __restrict__ hB, u64* __restrict__ HB,
    unsigned* __restrict__ flags) {
  constexpr int LDSP = 1544;
  __shared__ u16 ldsW[16 * LDSP];  // 49.4 KB
  __shared__ float glds[16][69];   // stride 69: write conflicts <=2-way (free)

  const int tid = threadIdx.x;
  const int lane = tid & 63, wv = tid >> 6;
  const int l15 = lane & 15, quad = lane >> 4, kq = quad * 8;
  const int Mb = wv * 16;
  const int wg = blockIdx.x;
  const int hc0 = wg * 4;
  const int arow = Mb + l15;

  // stage encoder weights: LDS row c=g*4+j <- WtE col g*1024+hc0+j
  for (int i = tid; i < 16 * 192; i += 256) {
    const int c = i / 192, ch = i % 192;
    const int g = c >> 2, j = c & 3;
    *(bf16x8_a*)&ldsW[c * LDSP + ch * 8] =
        ldb8(WtE + (size_t)(g * 1024 + hc0 + j) * 1536 + ch * 8);
  }
  // biases: wave-0 threads own one batch row, all 4 hc cells
  float bi4[4], bf4[4], bg4[4], bo4[4], cst4[4];
#pragma unroll
  for (int j = 0; j < 4; ++j) {
    bi4[j] = encB[hc0 + j];
    bf4[j] = encB[1024 + hc0 + j];
    bg4[j] = encB[2048 + hc0 + j];
    bo4[j] = encB[3072 + hc0 + j];
    cst4[j] = 0.0f;
  }
  __syncthreads();

  f32x4 acc[4];
  acc[0] = (f32x4){0.f, 0.f, 0.f, 0.f};
  acc[1] = acc[0]; acc[2] = acc[0]; acc[3] = acc[0];
  {  // x_gemm(t=0) prologue
    const float* er = emb + (size_t)src[arow * 512 + 0] * 512 + kq;
    const u16* wx = &ldsW[l15 * LDSP + kq];
#pragma unroll
    for (int i = 0; i < 16; ++i)
      acc[i & 3] = MFMA16(cvt8(er + i * 32), ldb8(wx + i * 32), acc[i & 3]);
  }

  // ==================== encoder: 512 steps ====================
  for (int t = 0; t < 512; ++t) {
    const unsigned ep = (unsigned)t;
    if (wv == 0) {  // wave-0 poll: lane checks 4 flags
      const unsigned* fp = flags + (lane << 2);
      for (;;) {
        unsigned m0 = AGLD(fp + 0), m1 = AGLD(fp + 1);
        unsigned m2 = AGLD(fp + 2), m3 = AGLD(fp + 3);
        unsigned a_ = m0 < m1 ? m0 : m1, b_ = m2 < m3 ? m2 : m3;
        unsigned mn = a_ < b_ ? a_ : b_;
        if (__all((int)(mn >= ep))) break;
        __builtin_amdgcn_s_sleep(1);
      }
    }
    __syncthreads();
    // acquire: drains + buffer_inv (L1+L2) -> normal loads below see fresh L3
    __builtin_amdgcn_fence(__ATOMIC_ACQUIRE, "agent");

    const u64* hin = (t & 1) ? hB : hA;
    u64* hout = (t == 511) ? HB : ((t & 1) ? hA : hB);

    // ---- prefetch ALL h A-fragments (normal cached loads; L2-shared per XCD)
    u64 qa[64];
#pragma unroll
    for (int ks = 0; ks < 32; ++ks) {
      const int c0 = ks * 512 + (quad << 7) + arow;
      qa[2 * ks] = ((const u64_a*)hin)[c0];
      qa[2 * ks + 1] = ((const u64_a*)hin)[c0 + 64];
    }
    const u16* wl = &ldsW[l15 * LDSP + 512 + kq];
#pragma unroll
    for (int i = 0; i < 32; ++i)
      acc[i & 3] = MFMA16(mk8(qa[2 * i], qa[2 * i + 1]), ldb8(wl + i * 32), acc[i & 3]);

    f32x4 asum = (acc[0] + acc[1]) + (acc[2] + acc[3]);
#pragma unroll
    for (int r = 0; r < 4; ++r) glds[l15][Mb + quad * 4 + r] = asum[r];
    __syncthreads();

    // ---- wave-0 epilogue: thread b = tid does all 4 cells of its row
    if (tid < 64) {
      const int b = tid;
      U16B hp;
#pragma unroll
      for (int j = 0; j < 4; ++j) {
        const float gi = glds[j][b] + bi4[j];
        const float gf = glds[4 + j][b] + bf4[j];
        const float gg = glds[8 + j][b] + bg4[j];
        const float go = glds[12 + j][b] + bo4[j];
        const float iv = sigmoid_(gi), fv = sigmoid_(gf), gv = tanh_(gg), ov = sigmoid_(go);
        cst4[j] = fv * cst4[j] + iv * gv;
        hp.h[j] = f2bf_rne(ov * tanh_(cst4[j]));
      }
      AGST(hout + (wg << 6) + b, hp.q[0]);
      asm volatile("s_waitcnt vmcnt(0)" ::: "memory");
      if (tid == 0) AGST(&flags[wg], ep + 1);
    }

    // ---- overlap barrier window with next step's x-phase (no h dependency)
    acc[0] = (f32x4){0.f, 0.f, 0.f, 0.f};
    acc[1] = acc[0]; acc[2] = acc[0]; acc[3] = acc[0];
    if (t < 511) {
      const float* er = emb + (size_t)src[arow * 512 + (t + 1)] * 512 + kq;
      const u16* wx = &ldsW[l15 * LDSP + kq];
#pragma unroll
      for (int i = 0; i < 16; ++i)
        acc[i & 3] = MFMA16(cvt8(er + i * 32), ldb8(wx + i * 32), acc[i & 3]);
    }
  }

  // ---- swap to decoder weights + biases
  for (int i = tid; i < 16 * 136; i += 256) {
    const int c = i / 136, ch = i % 136;
    const int g = c >> 2, j = c & 3;
    *(bf16x8_a*)&ldsW[c * LDSP + ch * 8] =
        ldb8(WtD + (size_t)(g * 1024 + hc0 + j) * 1088 + ch * 8);
  }
#pragma unroll
  for (int j = 0; j < 4; ++j) {
    bi4[j] = decB[hc0 + j];
    bf4[j] = decB[1024 + hc0 + j];
    bg4[j] = decB[2048 + hc0 + j];
    bo4[j] = decB[3072 + hc0 + j];
  }
  __syncthreads();

  // ==================== decoder: 512 steps ====================
  for (int t = 0; t < 512; ++t) {
    const unsigned ep = (unsigned)(512 + t);
    if (wv == 0) {
      const unsigned* fp = flags + (lane << 2);
      for (;;) {
        unsigned m0 = AGLD(fp + 0), m1 = AGLD(fp + 1);
        unsigned m2 = AGLD(fp + 2), m3 = AGLD(fp + 3);
        unsigned a_ = m0 < m1 ? m0 : m1, b_ = m2 < m3 ? m2 : m3;
        unsigned mn = a_ < b_ ? a_ : b_;
        if (__all((int)(mn >= ep))) break;
        __builtin_amdgcn_s_sleep(1);
      }
    }
    __syncthreads();
    __builtin_amdgcn_fence(__ATOMIC_ACQUIRE, "agent");

    const u64* hin = HB + (size_t)t * 16384;
    u64* hout = HB + (size_t)(t + 1) * 16384;

    int tok = 0;
    if (tid < 64) tok = trg[tid * 512 + t];  // early: hide L3 latency behind qa

    u64 qa[64];
#pragma unroll
    for (int ks = 0; ks < 32; ++ks) {
      const int c0 = ks * 512 + (quad << 7) + arow;
      qa[2 * ks] = ((const u64_a*)hin)[c0];
      qa[2 * ks + 1] = ((const u64_a*)hin)[c0 + 64];
    }
    acc[0] = (f32x4){0.f, 0.f, 0.f, 0.f};
    acc[1] = acc[0]; acc[2] = acc[0]; acc[3] = acc[0];
    const u16* wl = &ldsW[l15 * LDSP + 64 + kq];
#pragma unroll
    for (int i = 0; i < 32; ++i)
      acc[i & 3] = MFMA16(mk8(qa[2 * i], qa[2 * i + 1]), ldb8(wl + i * 32), acc[i & 3]);

    f32x4 asum = (acc[0] + acc[1]) + (acc[2] + acc[3]);
#pragma unroll
    for (int r = 0; r < 4; ++r) glds[l15][Mb + quad * 4 + r] = asum[r];
    __syncthreads();

    if (tid < 64) {  // cell + one-hot gather from LDS weights (z row = trg token)
      const int b = tid;
      U16B hp;
#pragma unroll
      for (int j = 0; j < 4; ++j) {
        const float gi = glds[j][b] + bi4[j] + bf2f(ldsW[j * LDSP + tok]);
        const float gf = glds[4 + j][b] + bf4[j] + bf2f(ldsW[(4 + j) * LDSP + tok]);
        const float gg = glds[8 + j][b] + bg4[j] + bf2f(ldsW[(8 + j) * LDSP + tok]);
        const float go = glds[12 + j][b] + bo4[j] + bf2f(ldsW[(12 + j) * LDSP + tok]);
        const float iv = sigmoid_(gi), fv = sigmoid_(gf), gv = tanh_(gg), ov = sigmoid_(go);
        cst4[j] = fv * cst4[j] + iv * gv;
        hp.h[j] = f2bf_rne(ov * tanh_(cst4[j]));
      }
      AGST(hout + (wg << 6) + b, hp.q[0]);
      asm volatile("s_waitcnt vmcnt(0)" ::: "memory");
      if (tid == 0) AGST(&flags[wg], ep + 1);
    }
  }
}

// ==================== fallback per-step kernels (chunked h layout) ====================
__global__ __launch_bounds__(256) void enc_step_k(
    const float* __restrict__ emb, const int* __restrict__ src, int t,
    const u64* __restrict__ hin, const u16* __restrict__ Wt,
    const float* __restrict__ bias, float* __restrict__ cst, u16* __restrict__ hout) {
  const int tid = threadIdx.x;
  const int lane = tid & 63, wv = tid >> 6;
  const int l15 = lane & 15, quad = lane >> 4, kq = quad * 8;
  const int hc0 = blockIdx.x * 16;
  const int Mb = (wv & 1) * 32;
  const int Ng = wv >> 1;
  __shared__ float glds[64][65];
  f32x4 acc[2][2] = {{{0.f, 0.f, 0.f, 0.f}, {0.f, 0.f, 0.f, 0.f}},
                     {{0.f, 0.f, 0.f, 0.f}, {0.f, 0.f, 0.f, 0.f}}};
  const u16* wr0 = Wt + (size_t)((Ng * 2 + 0) * 1024 + hc0 + l15) * 1536;
  const u16* wr1 = Wt + (size_t)((Ng * 2 + 1) * 1024 + hc0 + l15) * 1536;
  const int b0 = Mb + l15, b1 = Mb + 16 + l15;
  const float* er0 = emb + (size_t)src[b0 * 512 + t] * 512;
  const float* er1 = emb + (size_t)src[b1 * 512 + t] * 512;
#pragma unroll 4
  for (int ks = 0; ks < 16; ++ks) {
    const int k = ks * 32 + kq;
    bf16x8 a0 = cvt8(er0 + k), a1 = cvt8(er1 + k);
    bf16x8 q0 = ldb8(wr0 + k), q1 = ldb8(wr1 + k);
    acc[0][0] = MFMA16(a0, q0, acc[0][0]);
    acc[0][1] = MFMA16(a0, q1, acc[0][1]);
    acc[1][0] = MFMA16(a1, q0, acc[1][0]);
    acc[1][1] = MFMA16(a1, q1, acc[1][1]);
  }
#pragma unroll 4
  for (int ks = 0; ks < 32; ++ks) {
    const int k = ks * 32 + kq;
    bf16x8 a0 = ld_chunk(hin, ks, quad, b0);
    bf16x8 a1 = ld_chunk(hin, ks, quad, b1);
    bf16x8 q0 = ldb8(wr0 + 512 + k), q1 = ldb8(wr1 + 512 + k);
    acc[0][0] = MFMA16(a0, q0, acc[0][0]);
    acc[0][1] = MFMA16(a0, q1, acc[0][1]);
    acc[1][0] = MFMA16(a1, q0, acc[1][0]);
    acc[1][1] = MFMA16(a1, q1, acc[1][1]);
  }
#pragma unroll
  for (int mt = 0; mt < 2; ++mt)
#pragma unroll
    for (int nt = 0; nt < 2; ++nt)
#pragma unroll
      for (int r = 0; r < 4; ++r)
        glds[Ng * 32 + nt * 16 + l15][Mb + mt * 16 + quad * 4 + r] = acc[mt][nt][r];
  __syncthreads();
  const int hcl = tid & 15, bg = tid >> 4;
  const int hc = hc0 + hcl;
  const float bi = bias[hc], bf_ = bias[1024 + hc], bgg = bias[2048 + hc], bo = bias[3072 + hc];
#pragma unroll
  for (int r = 0; r < 4; ++r) {
    const int b = bg * 4 + r;
    const float gi = glds[hcl][b] + bi;
    const float gf = glds[16 + hcl][b] + bf_;
    const float gg = glds[32 + hcl][b] + bgg;
    const float go = glds[48 + hcl][b] + bo;
    const float i_ = sigmoid_(gi), f_ = sigmoid_(gf), g_ = tanh_(gg), o_ = sigmoid_(go);
    const float cn = f_ * cst[(size_t)b * 1024 + hc] + i_ * g_;
    cst[(size_t)b * 1024 + hc] = cn;
    hout[(hc >> 2) * 256 + b * 4 + (hc & 3)] = f2bf_rne(o_ * tanh_(cn));
  }
}

__global__ __launch_bounds__(256) void dec_step_k(
    const int* __restrict__ trg, int t,
    const u64* __restrict__ hin, const u16* __restrict__ Wt,
    const float* __restrict__ bias, float* __restrict__ cst, u16* __restrict__ hout) {
  const int tid = threadIdx.x;
  const int lane = tid & 63, wv = tid >> 6;
  const int l15 = lane & 15, quad = lane >> 4, kq = quad * 8;
  const int hc0 = blockIdx.x * 16;
  const int Mb = (wv & 1) * 32;
  const int Ng = wv >> 1;
  __shared__ float glds[64][65];
  f32x4 acc[2][2] = {{{0.f, 0.f, 0.f, 0.f}, {0.f, 0.f, 0.f, 0.f}},
                     {{0.f, 0.f, 0.f, 0.f}, {0.f, 0.f, 0.f, 0.f}}};
  const u16* wr0 = Wt + (size_t)((Ng * 2 + 0) * 1024 + hc0 + l15) * 1088;
  const u16* wr1 = Wt + (size_t)((Ng * 2 + 1) * 1024 + hc0 + l15) * 1088;
  const int b0 = Mb + l15, b1 = Mb + 16 + l15;
#pragma unroll 4
  for (int ks = 0; ks < 32; ++ks) {
    const int k = ks * 32 + kq;
    bf16x8 a0 = ld_chunk(hin, ks, quad, b0);
    bf16x8 a1 = ld_chunk(hin, ks, quad, b1);
    bf16x8 q0 = ldb8(wr0 + 64 + k), q1 = ldb8(wr1 + 64 + k);
    acc[0][0] = MFMA16(a0, q0, acc[0][0]);
    acc[0][1] = MFMA16(a0, q1, acc[0][1]);
    acc[1][0] = MFMA16(a1, q0, acc[1][0]);
    acc[1][1] = MFMA16(a1, q1, acc[1][1]);
  }
#pragma unroll
  for (int mt = 0; mt < 2; ++mt)
#pragma unroll
    for (int nt = 0; nt < 2; ++nt)
#pragma unroll
      for (int r = 0; r < 4; ++r)
        glds[Ng * 32 + nt * 16 + l15][Mb + mt * 16 + quad * 4 + r] = acc[mt][nt][r];
  __syncthreads();
  const int hcl = tid & 15, bg = tid >> 4;
  const int hc = hc0 + hcl;
  const float bi = bias[hc], bf_ = bias[1024 + hc], bgg = bias[2048 + hc], bo = bias[3072 + hc];
#pragma unroll
  for (int r = 0; r < 4; ++r) {
    const int b = bg * 4 + r;
    const int tok = trg[b * 512 + t];
    const float gi = glds[hcl][b] + bi + bf2f(Wt[(size_t)(hc)*1088 + tok]);
    const float gf = glds[16 + hcl][b] + bf_ + bf2f(Wt[(size_t)(1024 + hc) * 1088 + tok]);
    const float gg = glds[32 + hcl][b] + bgg + bf2f(Wt[(size_t)(2048 + hc) * 1088 + tok]);
    const float go = glds[48 + hcl][b] + bo + bf2f(Wt[(size_t)(3072 + hc) * 1088 + tok]);
    const float i_ = sigmoid_(gi), f_ = sigmoid_(gf), g_ = tanh_(gg), o_ = sigmoid_(go);
    const float cn = f_ * cst[(size_t)b * 1024 + hc] + i_ * g_;
    cst[(size_t)b * 1024 + hc] = cn;
    hout[(hc >> 2) * 256 + b * 4 + (hc & 3)] = f2bf_rne(o_ * tanh_(cn));
  }
}

// ---------- final FC over all 32768 (t,b) rows, chunked h input ----------
__global__ __launch_bounds__(256) void fc_k(const u64* __restrict__ HBc,
                                            const u16* __restrict__ Wt,
                                            const float* __restrict__ fcb,
                                            float* __restrict__ out) {
  const int tid = threadIdx.x, lane = tid & 63, wv = tid >> 6;
  const int l15 = lane & 15, quad = lane >> 4, kq = quad * 8;
  const int r0 = blockIdx.x * 64 + wv * 16;
  const int t = r0 >> 6;                 // fixed per wave (r0 multiple of 16)
  const int b = (r0 & 63) + l15;         // A-row within the step
  const u64* ab = HBc + (size_t)(t + 1) * 16384;
  const u16* br0 = Wt + (size_t)(0 * 16 + l15) * 1024;
  const u16* br1 = Wt + (size_t)(1 * 16 + l15) * 1024;
  const u16* br2 = Wt + (size_t)(2 * 16 + l15) * 1024;
  const u16* br3 = Wt + (size_t)(3 * 16 + l15) * 1024;
  f32x4 acc[4] = {{0.f, 0.f, 0.f, 0.f}, {0.f, 0.f, 0.f, 0.f},
                  {0.f, 0.f, 0.f, 0.f}, {0.f, 0.f, 0.f, 0.f}};
#pragma unroll 4
  for (int ks = 0; ks < 32; ++ks) {
    const int k = ks * 32 + kq;
    bf16x8 a = ld_chunk(ab, ks, quad, b);
    acc[0] = MFMA16(a, ldb8(br0 + k), acc[0]);
    acc[1] = MFMA16(a, ldb8(br1 + k), acc[1]);
    acc[2] = MFMA16(a, ldb8(br2 + k), acc[2]);
    acc[3] = MFMA16(a, ldb8(br3 + k), acc[3]);
  }
#pragma unroll
  for (int nt = 0; nt < 4; ++nt) {
    const int tag = nt * 16 + l15;
    const float bb = fcb[tag];
#pragma unroll
    for (int r = 0; r < 4; ++r) {
      const int rr = r0 + quad * 4 + r;
      const int tt = rr >> 6, bo_ = rr & 63;
      out[(size_t)bo_ * 32768 + (size_t)tt * 64 + tag] = acc[nt][r] + bb;
    }
  }
}

// ---------- launch ----------
extern "C" void kernel_launch(void* const* d_in, const int* in_sizes, int n_in,
                              void* d_out, int out_size, void* d_ws, size_t ws_size,
                              hipStream_t stream) {
  const int* src = (const int*)d_in[0];
  const int* trg = (const int*)d_in[1];
  const float* emb = (const float*)d_in[2];
  const float* encW = (const float*)d_in[3];
  const float* encB = (const float*)d_in[4];
  const float* decW = (const float*)d_in[5];
  const float* decB = (const float*)d_in[6];
  const float* fcW = (const float*)d_in[7];
  const float* fcB = (const float*)d_in[8];
  float* out = (float*)d_out;

  // ws layout — identical offsets to rounds 1-4 (proven to fit)
  const size_t OFF_WTE = 0;          // 12,582,912
  const size_t OFF_WTD = 12582912;   //  8,912,896
  const size_t OFF_WTF = 21495808;   //    131,072
  const size_t OFF_HA = 21626880;    //    131,072
  const size_t OFF_HB2 = 21757952;   //    131,072
  const size_t OFF_C = 21889024;     //    262,144 (flags | fallback c-state)
  const size_t OFF_HALL = 22151168;  // 67,239,936
  const size_t NEEDED = 89391104;
  if (ws_size < NEEDED) return;

  char* w = (char*)d_ws;
  u16* WtE = (u16*)(w + OFF_WTE);
  u16* WtD = (u16*)(w + OFF_WTD);
  u16* WtF = (u16*)(w + OFF_WTF);
  u64* hA = (u64*)(w + OFF_HA);
  u64* hB = (u64*)(w + OFF_HB2);
  unsigned* flags = (unsigned*)(w + OFF_C);
  float* cs = (float*)(w + OFF_C);  // fallback only (aliases flags; paths exclusive)
  u64* HB = (u64*)(w + OFF_HALL);   // chunked: 513 steps x 16384 u64

  hipMemsetAsync(hA, 0, 131072, stream);
  hipMemsetAsync((void*)flags, 0, 262144, stream);

  transpose_cvt<<<dim3(128, 48), 256, 0, stream>>>(encW, WtE, 1536, 4096);
  transpose_cvt<<<dim3(128, 34), 256, 0, stream>>>(decW, WtD, 1088, 4096);
  transpose_cvt<<<dim3(2, 32), 256, 0, stream>>>(fcW, WtF, 1024, 64);

  void* args[] = {(void*)&emb, (void*)&src, (void*)&trg, (void*)&WtE, (void*)&WtD,
                  (void*)&encB, (void*)&decB, (void*)&hA, (void*)&hB, (void*)&HB,
                  (void*)&flags};
  hipError_t e = hipLaunchCooperativeKernel((const void*)rnn_persist, dim3(256), dim3(256),
                                            args, 0, stream);
  if (e != hipSuccess) {
    // fallback: per-step path (chunked h layout)
    for (int t = 0; t < 512; ++t) {
      const u64* hin = (t & 1) ? hB : hA;
      u64* hout = (t == 511) ? HB : ((t & 1) ? hA : hB);
      enc_step_k<<<64, 256, 0, stream>>>(emb, src, t, hin, WtE, encB, cs, (u16*)hout);
    }
    for (int t = 0; t < 512; ++t) {
      dec_step_k<<<64, 256, 0, stream>>>(trg, t, HB + (size_t)t * 16384, WtD, decB, cs,
                                         (u16*)(HB + (size_t)(t + 1) * 16384));
    }
  }
  fc_k<<<512, 256, 0, stream>>>(HB, WtF, fcB, out);
}